// Round 10
// baseline (9098.409 us; speedup 1.0000x reference)
//
#include <hip/hip_runtime.h>

typedef _Float16 half_t;
typedef _Float16 half2_t __attribute__((ext_vector_type(2)));
typedef _Float16 half4_t __attribute__((ext_vector_type(4)));
typedef _Float16 half8_t __attribute__((ext_vector_type(8)));
typedef float    floatx4 __attribute__((ext_vector_type(4)));

#define T_SEQ 2048
#define EDIM  512

// workspace layout (bytes). total required ~72.9 MB
static constexpr size_t EMB_OFF  = 0;                        // 32*2048*512 f16 = 67,108,864
static constexpr size_t Q_OFF    = 67108864;                 // 2048*512 f16 (x16 aliased during LSTM)
static constexpr size_t WQ_OFF   = Q_OFF  + 2097152;
static constexpr size_t WK_OFF   = WQ_OFF + 524288;
static constexpr size_t WV_OFF   = WK_OFF + 524288;
static constexpr size_t WO_OFF   = WV_OFF + 524288;
static constexpr size_t TE_OFF   = WO_OFF + 524288;          // end 71,335,936
static constexpr size_t WIHF_OFF = TE_OFF + 32768;           // 32*1024*12 f16 = 786,432
static constexpr size_t WIHB_OFF = WIHF_OFF + 786432;        // end 72,908,800

__device__ __forceinline__ float fdot2f(half2_t a, half2_t b, float c) {
#if __has_builtin(__builtin_amdgcn_fdot2)
  return __builtin_amdgcn_fdot2(a, b, c, false);
#else
  return c + (float)a[0] * (float)b[0] + (float)a[1] * (float)b[1];
#endif
}
__device__ __forceinline__ half2_t mkh2(float a, float b) {
  half2_t r; r[0] = (half_t)a; r[1] = (half_t)b; return r;
}
__device__ __forceinline__ half2_t h2bc(unsigned u) { return __builtin_bit_cast(half2_t, u); }
__device__ __forceinline__ float sigm(float v)  { return __builtin_amdgcn_rcpf(1.f + __expf(-v)); }
__device__ __forceinline__ float tanhf_(float v){ return __builtin_amdgcn_rcpf(1.f + __expf(-2.f * v)) * 2.f - 1.f; }

// ---------------------------------------------------------------------------
// convert fp32 -> f16: attn weights, type_emb, x, and W_ih (both dirs)
// elems: 4*262144 + 16384 + 786432 + 2*393216 = 2,637,824 ; /4/256 = 2576 blocks
__global__ void convert_kernel(const float* __restrict__ wq, const float* __restrict__ wk,
                               const float* __restrict__ wvv, const float* __restrict__ wo,
                               const float* __restrict__ te, const float* __restrict__ x,
                               const float* __restrict__ wihf, const float* __restrict__ wihb,
                               half_t* __restrict__ wq16, half_t* __restrict__ wk16,
                               half_t* __restrict__ wv16, half_t* __restrict__ wo16,
                               half_t* __restrict__ te16, half_t* __restrict__ x16,
                               half_t* __restrict__ wihf16, half_t* __restrict__ wihb16) {
  int i4 = (blockIdx.x * 256 + threadIdx.x) * 4;
  const float* src; half_t* dst; int off;
  if      (i4 < 262144)      { src = wq;   dst = wq16;   off = i4; }
  else if (i4 < 524288)      { src = wk;   dst = wk16;   off = i4 - 262144; }
  else if (i4 < 786432)      { src = wvv;  dst = wv16;   off = i4 - 524288; }
  else if (i4 < 1048576)     { src = wo;   dst = wo16;   off = i4 - 786432; }
  else if (i4 < 1064960)     { src = te;   dst = te16;   off = i4 - 1048576; }
  else if (i4 < 1851392)     { src = x;    dst = x16;    off = i4 - 1064960; }
  else if (i4 < 2244608)     { src = wihf; dst = wihf16; off = i4 - 1851392; }
  else                       { src = wihb; dst = wihb16; off = i4 - 2244608; }
  float4 v = *(const float4*)(src + off);
  half4_t h; h[0] = (half_t)v.x; h[1] = (half_t)v.y; h[2] = (half_t)v.z; h[3] = (half_t)v.w;
  *(half4_t*)(dst + off) = h;
}

// ---------------------------------------------------------------------------
// MFMA LSTM. One (branch,dir) chain per block, 512 threads (8 waves, 2/SIMD,
// unified 256 regs/wave per the R1/R4/R9-measured allocator law).
// Per wave w: units u = w*32 + nt*16 + (lane&15), nt=0,1. Four gate matmuls
// via mfma_f32_16x16x32_f16 per k-chunk: A = h broadcast into ALL 16 rows
// (every lane loads the same k-slice), so every D row equals the true gate
// value -> each lane's acc[g][nt][0] is the gate for its own column. No
// gate-LDS round trip, no row extraction (R8's flaw). B fragments (weights)
// are MFMA-only operands -> allocator banks them in AGPRs where MFMA reads
// them at zero VALU cost (the only free path to the second half of the
// 512-reg unified file; R4-R7 paid v_accvgpr_read per use).
// Budget/wave: bfragR 45 frags =180 regs + acc 32 + working ~40 = 252 <= 256.
// LDS: 19 frags/wave = 152 KB + hbuf 1 KB. One barrier per step.
#define LSTM_LDS_BYTES (8 * 19 * 1024 + 1024)   // 156,672 <= 163,840

__global__ __launch_bounds__(512, 1)
void lstm_kernel(const half_t* __restrict__ x16,
                 const half_t* __restrict__ wihf16, const half_t* __restrict__ wihb16,
                 const float* __restrict__ whh_f, const float* __restrict__ whh_b,
                 const float* __restrict__ b_f, const float* __restrict__ b_b,
                 half_t* __restrict__ emb) {
  extern __shared__ char smem[];
  char*   frag_lds = smem;                       // [8 waves][19 frags][64 lanes][16B]
  half_t* hbuf     = (half_t*)(smem + 155648);   // [2][256]

  const int bid = blockIdx.x, br = bid >> 1, dir = bid & 1;
  const int tid = threadIdx.x, lane = tid & 63, w = tid >> 6;
  const int cl = lane & 15, kg = lane >> 4;
  const half_t* wih16 = dir ? wihb16 : wihf16;
  const float*  whh   = dir ? whh_b  : whh_f;
  const float*  bias  = dir ? b_b    : b_f;
  const half_t* wihc  = wih16 + (size_t)br * 1024 * 12;

  // ---- stage B fragments: f = kc*8 + g*2 + nt; f<45 -> regs, else LDS ----
  half8_t bfragR[45];
#pragma unroll
  for (int f = 0; f < 64; ++f) {
    const int kc = f >> 3, g = (f >> 1) & 3, nt = f & 1;
    const int row = g * 256 + w * 32 + nt * 16 + cl;
    const float* s = whh + ((size_t)br * 1024 + row) * 256 + kc * 32 + kg * 8;
    float4 a = *(const float4*)s, b = *(const float4*)(s + 4);
    half8_t h8;
    h8[0] = (half_t)a.x; h8[1] = (half_t)a.y; h8[2] = (half_t)a.z; h8[3] = (half_t)a.w;
    h8[4] = (half_t)b.x; h8[5] = (half_t)b.y; h8[6] = (half_t)b.z; h8[7] = (half_t)b.w;
    if (f < 45) bfragR[f] = h8;
    else *(uint4*)(frag_lds + (((w * 19 + (f - 45)) * 64) + lane) * 16) =
           __builtin_bit_cast(uint4, h8);
  }

  // ---- loop-invariant bias ----
  float bb[4][2];
#pragma unroll
  for (int g = 0; g < 4; ++g)
#pragma unroll
    for (int nt = 0; nt < 2; ++nt)
      bb[g][nt] = bias[(size_t)br * 1024 + g * 256 + w * 32 + nt * 16 + cl];

  hbuf[tid] = (half_t)0.f;   // 512 entries == blockDim: h_{-1}=0 both buffers

  // ---- x pipeline: xh holds x(tin(s+1)) during step s ----
  half2_t xh[6];
  {
    const int t0 = dir ? 2047 : 0;
    const uint2* xp = (const uint2*)(x16 + ((size_t)br * T_SEQ + t0) * 12);
    uint2 u0 = xp[0], u1 = xp[1], u2 = xp[2];
    xh[0] = h2bc(u0.x); xh[1] = h2bc(u0.y);
    xh[2] = h2bc(u1.x); xh[3] = h2bc(u1.y);
    xh[4] = h2bc(u2.x); xh[5] = h2bc(u2.y);
  }

  // ---- prologue: xw for step 0 -> acc reg0; regs 1-3 zeroed ----
  floatx4 acc[4][2];
#pragma unroll
  for (int g = 0; g < 4; ++g)
#pragma unroll
    for (int nt = 0; nt < 2; ++nt) {
      float p = bb[g][nt];
      const half_t* wr = wihc + (g * 256 + w * 32 + nt * 16 + cl) * 12;
      uint2 v0 = *(const uint2*)wr, v1 = *(const uint2*)(wr + 4), v2 = *(const uint2*)(wr + 8);
      p = fdot2f(h2bc(v0.x), xh[0], p); p = fdot2f(h2bc(v0.y), xh[1], p);
      p = fdot2f(h2bc(v1.x), xh[2], p); p = fdot2f(h2bc(v1.y), xh[3], p);
      p = fdot2f(h2bc(v2.x), xh[4], p); p = fdot2f(h2bc(v2.y), xh[5], p);
      acc[g][nt] = floatx4{p, 0.f, 0.f, 0.f};
    }
  {
    const int t1 = dir ? 2046 : 1;
    const uint2* xp = (const uint2*)(x16 + ((size_t)br * T_SEQ + t1) * 12);
    uint2 u0 = xp[0], u1 = xp[1], u2 = xp[2];
    xh[0] = h2bc(u0.x); xh[1] = h2bc(u0.y);
    xh[2] = h2bc(u1.x); xh[3] = h2bc(u1.y);
    xh[4] = h2bc(u2.x); xh[5] = h2bc(u2.y);
  }
  float c0 = 0.f, c1 = 0.f;
  __syncthreads();

#pragma unroll 1
  for (int s = 0; s < T_SEQ; ++s) {
    const int cur = s & 1, nxt = cur ^ 1;

    // xw for step s+1 (loads issue early; latency hides under MFMA)
    float p[4][2];
#pragma unroll
    for (int g = 0; g < 4; ++g)
#pragma unroll
      for (int nt = 0; nt < 2; ++nt) {
        float pv = bb[g][nt];
        const half_t* wr = wihc + (g * 256 + w * 32 + nt * 16 + cl) * 12;
        uint2 v0 = *(const uint2*)wr, v1 = *(const uint2*)(wr + 4), v2 = *(const uint2*)(wr + 8);
        pv = fdot2f(h2bc(v0.x), xh[0], pv); pv = fdot2f(h2bc(v0.y), xh[1], pv);
        pv = fdot2f(h2bc(v1.x), xh[2], pv); pv = fdot2f(h2bc(v1.y), xh[3], pv);
        pv = fdot2f(h2bc(v2.x), xh[4], pv); pv = fdot2f(h2bc(v2.y), xh[5], pv);
        p[g][nt] = pv;
      }

    // MFMA: 8 k-chunks x (4 gates x 2 tiles). A = h broadcast (all rows equal).
#pragma unroll
    for (int kc = 0; kc < 8; ++kc) {
      half8_t A = *(const half8_t*)(hbuf + cur * 256 + kc * 32 + kg * 8);
#pragma unroll
      for (int g = 0; g < 4; ++g)
#pragma unroll
        for (int nt = 0; nt < 2; ++nt) {
          const int f = kc * 8 + g * 2 + nt;
          half8_t B = (f < 45) ? bfragR[f]
              : *(const half8_t*)(frag_lds + (((w * 19 + (f - 45)) * 64) + lane) * 16);
          acc[g][nt] = __builtin_amdgcn_mfma_f32_16x16x32_f16(A, B, acc[g][nt], 0, 0, 0);
        }
    }

    // update: every lane holds gates for its 2 units in acc[g][nt][0]
    float gi0 = acc[0][0][0], gf0 = acc[1][0][0], gg0 = acc[2][0][0], go0 = acc[3][0][0];
    float gi1 = acc[0][1][0], gf1 = acc[1][1][0], gg1 = acc[2][1][0], go1 = acc[3][1][0];
    c0 = sigm(gf0) * c0 + sigm(gi0) * tanhf_(gg0);
    c1 = sigm(gf1) * c1 + sigm(gi1) * tanhf_(gg1);
    float h0 = sigm(go0) * tanhf_(c0);
    float h1 = sigm(go1) * tanhf_(c1);

    // stores: lanes 0-15 write nt=0 units, lanes 16-31 write nt=1 units
    if (lane < 32) {
      const float hv = (lane < 16) ? h0 : h1;
      const half_t hh = (half_t)hv;
      const int u = w * 32 + kg * 16 + cl;   // kg in {0,1} here
      hbuf[nxt * 256 + u] = hh;
      const int tcur = dir ? (2047 - s) : s;
      emb[((size_t)br * T_SEQ + tcur) * EDIM + dir * 256 + u] = hh;
    }

    // re-arm acc reg0 with next step's xw (regs 1-3 accumulate unread garbage)
#pragma unroll
    for (int g = 0; g < 4; ++g)
#pragma unroll
      for (int nt = 0; nt < 2; ++nt)
        acc[g][nt][0] = p[g][nt];

    // rotate x pipeline: xh <- x(tin(s+2))
    {
      int q2 = s + 2; if (q2 > 2047) q2 = 2047;
      const int t2 = dir ? (2047 - q2) : q2;
      const uint2* xp = (const uint2*)(x16 + ((size_t)br * T_SEQ + t2) * 12);
      uint2 u0 = xp[0], u1 = xp[1], u2 = xp[2];
      xh[0] = h2bc(u0.x); xh[1] = h2bc(u0.y);
      xh[2] = h2bc(u1.x); xh[3] = h2bc(u1.y);
      xh[4] = h2bc(u2.x); xh[5] = h2bc(u2.y);
    }
    __syncthreads();
  }
}

// ---------------------------------------------------------------------------
__global__ __launch_bounds__(256, 1)
void qproj_kernel(const half_t* __restrict__ emb, const half_t* __restrict__ wq16,
                  const float* __restrict__ bq, half_t* __restrict__ q_ws) {
  const int t0 = blockIdx.x * 32;
  const int tid = threadIdx.x;
  const int lane = tid & 63, wid = tid >> 6;
  const int col = lane & 15, grp = lane >> 4;

  floatx4 acc[2][8];
#pragma unroll
  for (int nt = 0; nt < 8; ++nt) {
    int eo = wid * 128 + nt * 16 + col;
    float b = bq[eo];
#pragma unroll
    for (int mt = 0; mt < 2; ++mt) { acc[mt][nt][0] = b; acc[mt][nt][1] = b; acc[mt][nt][2] = b; acc[mt][nt][3] = b; }
  }
  for (int kc = 0; kc < 16; ++kc) {
    const int e = kc * 32 + grp * 8;
    half8_t a[2];
#pragma unroll
    for (int mt = 0; mt < 2; ++mt) {
      int trow = t0 + mt * 16 + col;
      a[mt] = *(const half8_t*)(emb + (size_t)trow * EDIM + e);
    }
#pragma unroll
    for (int nt = 0; nt < 8; ++nt) {
      int eo = wid * 128 + nt * 16 + col;
      half8_t bf = *(const half8_t*)(wq16 + (size_t)eo * EDIM + e);
#pragma unroll
      for (int mt = 0; mt < 2; ++mt)
        acc[mt][nt] = __builtin_amdgcn_mfma_f32_16x16x32_f16(a[mt], bf, acc[mt][nt], 0, 0, 0);
    }
  }
#pragma unroll
  for (int mt = 0; mt < 2; ++mt)
#pragma unroll
    for (int nt = 0; nt < 8; ++nt)
#pragma unroll
      for (int r = 0; r < 4; ++r) {
        int trow = t0 + mt * 16 + grp * 4 + r;
        int eo = wid * 128 + nt * 16 + col;
        q_ws[(size_t)trow * EDIM + eo] = (half_t)acc[mt][nt][r];
      }
}

// ---------------------------------------------------------------------------
__global__ __launch_bounds__(256, 1)
void attn_kernel(const half_t* __restrict__ emb, const half_t* __restrict__ q_ws,
                 const half_t* __restrict__ wk16, const half_t* __restrict__ wv16,
                 const half_t* __restrict__ wo16, const half_t* __restrict__ te16,
                 const float* __restrict__ bk, const float* __restrict__ bv,
                 const float* __restrict__ bo, float* __restrict__ out) {
  __shared__ float  scores_lds[128];
  __shared__ float  w_lds[128];
  __shared__ half_t ctx_lds[512];

  const int t = blockIdx.x;
  const int tid = threadIdx.x;
  const int lane = tid & 63, wid = tid >> 6;
  const int col = lane & 15, grp = lane >> 4;

  floatx4 kacc[2][8], vacc[2][8];
#pragma unroll
  for (int nt = 0; nt < 8; ++nt) {
    int eo = wid * 128 + nt * 16 + col;
    float kb = bk[eo], vb = bv[eo];
#pragma unroll
    for (int mt = 0; mt < 2; ++mt) {
      kacc[mt][nt][0] = kb; kacc[mt][nt][1] = kb; kacc[mt][nt][2] = kb; kacc[mt][nt][3] = kb;
      vacc[mt][nt][0] = vb; vacc[mt][nt][1] = vb; vacc[mt][nt][2] = vb; vacc[mt][nt][3] = vb;
    }
  }
  for (int kc = 0; kc < 16; ++kc) {
    const int e = kc * 32 + grp * 8;
    half8_t av[2], ak[2];
#pragma unroll
    for (int mt = 0; mt < 2; ++mt) {
      int branch = mt * 16 + col;
      av[mt] = *(const half8_t*)(emb + ((size_t)branch * T_SEQ + t) * EDIM + e);
      half8_t te = *(const half8_t*)(te16 + (size_t)branch * EDIM + e);
      ak[mt] = av[mt] + te;
    }
#pragma unroll
    for (int nt = 0; nt < 8; ++nt) {
      int eo = wid * 128 + nt * 16 + col;
      half8_t bkf = *(const half8_t*)(wk16 + (size_t)eo * EDIM + e);
      half8_t bvf = *(const half8_t*)(wv16 + (size_t)eo * EDIM + e);
#pragma unroll
      for (int mt = 0; mt < 2; ++mt) {
        kacc[mt][nt] = __builtin_amdgcn_mfma_f32_16x16x32_f16(ak[mt], bkf, kacc[mt][nt], 0, 0, 0);
        vacc[mt][nt] = __builtin_amdgcn_mfma_f32_16x16x32_f16(av[mt], bvf, vacc[mt][nt], 0, 0, 0);
      }
    }
  }

  float spart[8];
#pragma unroll
  for (int i = 0; i < 8; ++i) spart[i] = 0.f;
#pragma unroll
  for (int nt = 0; nt < 8; ++nt) {
    int eo = wid * 128 + nt * 16 + col;
    float qf = (float)q_ws[(size_t)t * EDIM + eo];
#pragma unroll
    for (int mt = 0; mt < 2; ++mt)
#pragma unroll
      for (int r = 0; r < 4; ++r)
        spart[mt * 4 + r] += qf * kacc[mt][nt][r];
  }
#pragma unroll
  for (int i = 0; i < 8; ++i) {
    float v = spart[i];
    v += __shfl_xor(v, 1); v += __shfl_xor(v, 2); v += __shfl_xor(v, 4); v += __shfl_xor(v, 8);
    spart[i] = v;
  }
  const float scale = 0.08838834764831845f;
  if (col == 0) {
#pragma unroll
    for (int mt = 0; mt < 2; ++mt)
#pragma unroll
      for (int r = 0; r < 4; ++r)
        scores_lds[wid * 32 + mt * 16 + grp * 4 + r] = spart[mt * 4 + r] * scale;
  }
  float sc = scores_lds[wid * 32 + (lane & 31)];
  float m = sc;
  m = fmaxf(m, __shfl_xor(m, 1));  m = fmaxf(m, __shfl_xor(m, 2));
  m = fmaxf(m, __shfl_xor(m, 4));  m = fmaxf(m, __shfl_xor(m, 8));
  m = fmaxf(m, __shfl_xor(m, 16));
  float ex = __expf(sc - m);
  float sm = ex;
  sm += __shfl_xor(sm, 1); sm += __shfl_xor(sm, 2); sm += __shfl_xor(sm, 4);
  sm += __shfl_xor(sm, 8); sm += __shfl_xor(sm, 16);
  float wn = ex * __builtin_amdgcn_rcpf(sm);
  if (lane < 32) w_lds[wid * 32 + lane] = wn;

  float wb[8];
#pragma unroll
  for (int mt = 0; mt < 2; ++mt)
#pragma unroll
    for (int r = 0; r < 4; ++r)
      wb[mt * 4 + r] = w_lds[wid * 32 + mt * 16 + grp * 4 + r];
#pragma unroll
  for (int nt = 0; nt < 8; ++nt) {
    float cx = 0.f;
#pragma unroll
    for (int mt = 0; mt < 2; ++mt)
#pragma unroll
      for (int r = 0; r < 4; ++r)
        cx += wb[mt * 4 + r] * vacc[mt][nt][r];
    cx += __shfl_xor(cx, 16);
    cx += __shfl_xor(cx, 32);
    float cxh = __shfl_xor(cx, 1);
    if ((lane < 16) && ((lane & 1) == 0))
      *(half2_t*)(ctx_lds + wid * 128 + nt * 16 + lane) = mkh2(cx, cxh);
  }
  __syncthreads();

  if (tid < 32) {
    float a = 0.25f * (w_lds[tid] + w_lds[32 + tid] + w_lds[64 + tid] + w_lds[96 + tid]);
    out[1048576 + (size_t)t * 32 + tid] = a;
  }
  const int eo2 = tid * 2;
  float o0 = bo[eo2], o1 = bo[eo2 + 1];
  const uint4* cl2 = (const uint4*)ctx_lds;
  const half_t* wrow0 = wo16 + (size_t)eo2 * EDIM;
  const half_t* wrow1 = wrow0 + EDIM;
#pragma unroll 8
  for (int c = 0; c < 64; ++c) {
    uint4 cv = cl2[c];
    uint4 w0 = *(const uint4*)(wrow0 + c * 8);
    uint4 w1 = *(const uint4*)(wrow1 + c * 8);
    half2_t c0 = h2bc(cv.x), c1 = h2bc(cv.y), c2 = h2bc(cv.z), c3 = h2bc(cv.w);
    o0 = fdot2f(h2bc(w0.x), c0, o0);
    o0 = fdot2f(h2bc(w0.y), c1, o0);
    o0 = fdot2f(h2bc(w0.z), c2, o0);
    o0 = fdot2f(h2bc(w0.w), c3, o0);
    o1 = fdot2f(h2bc(w1.x), c0, o1);
    o1 = fdot2f(h2bc(w1.y), c1, o1);
    o1 = fdot2f(h2bc(w1.z), c2, o1);
    o1 = fdot2f(h2bc(w1.w), c3, o1);
  }
  out[(size_t)t * EDIM + eo2]     = o0;
  out[(size_t)t * EDIM + eo2 + 1] = o1;
}

// ---------------------------------------------------------------------------
extern "C" void kernel_launch(void* const* d_in, const int* in_sizes, int n_in,
                              void* d_out, int out_size, void* d_ws, size_t ws_size,
                              hipStream_t stream) {
  const float* x    = (const float*)d_in[0];
  const float* wihf = (const float*)d_in[1];
  const float* whhf = (const float*)d_in[2];
  const float* bf   = (const float*)d_in[3];
  const float* wihb = (const float*)d_in[4];
  const float* whhb = (const float*)d_in[5];
  const float* bbv  = (const float*)d_in[6];
  const float* te   = (const float*)d_in[7];
  const float* wq   = (const float*)d_in[8];
  const float* bq   = (const float*)d_in[9];
  const float* wk   = (const float*)d_in[10];
  const float* bk   = (const float*)d_in[11];
  const float* wvv  = (const float*)d_in[12];
  const float* bv   = (const float*)d_in[13];
  const float* wo   = (const float*)d_in[14];
  const float* bo   = (const float*)d_in[15];
  float* out = (float*)d_out;

  char* ws = (char*)d_ws;
  half_t* emb    = (half_t*)(ws + EMB_OFF);
  half_t* q_ws   = (half_t*)(ws + Q_OFF);
  half_t* x16    = (half_t*)(ws + Q_OFF);     // aliased during LSTM phase
  half_t* wq16   = (half_t*)(ws + WQ_OFF);
  half_t* wk16   = (half_t*)(ws + WK_OFF);
  half_t* wv16   = (half_t*)(ws + WV_OFF);
  half_t* wo16   = (half_t*)(ws + WO_OFF);
  half_t* te16   = (half_t*)(ws + TE_OFF);
  half_t* wihf16 = (half_t*)(ws + WIHF_OFF);
  half_t* wihb16 = (half_t*)(ws + WIHB_OFF);

  convert_kernel<<<2576, 256, 0, stream>>>(wq, wk, wvv, wo, te, x, wihf, wihb,
                                           wq16, wk16, wv16, wo16, te16, x16,
                                           wihf16, wihb16);

  (void)hipFuncSetAttribute((const void*)lstm_kernel,
                            hipFuncAttributeMaxDynamicSharedMemorySize, LSTM_LDS_BYTES);
  lstm_kernel<<<64, 512, LSTM_LDS_BYTES, stream>>>(x16, wihf16, wihb16,
                                                   whhf, whhb, bf, bbv, emb);

  qproj_kernel<<<64, 256, 0, stream>>>(emb, wq16, bq, q_ws);

  attn_kernel<<<2048, 256, 0, stream>>>(emb, q_ws, wk16, wv16, wo16, te16, bk, bv, bo, out);
}